// Round 5
// baseline (74.618 us; speedup 1.0000x reference)
//
#include <hip/hip_runtime.h>
#include <hip/hip_bf16.h>
#include <cmath>

typedef __attribute__((ext_vector_type(8))) short short8;
typedef __attribute__((ext_vector_type(4))) float f32x4;

#define EPS_F 1e-7f
#define NEG_DIAG_F -10.0f

#define BM 128
#define BN 64
#define BK 64
#define NTHREADS 256
#define NPART 96            // 64 direct slots + 32 transposed slots per row

__device__ __forceinline__ void gload_lds16(const void* gptr, void* ldsptr) {
    __builtin_amdgcn_global_load_lds(
        (const __attribute__((address_space(1))) unsigned int*)gptr,
        (__attribute__((address_space(3))) unsigned int*)ldsptr,
        16, 0, 0);
}

// 4x4 transpose among lanes q=lr&3 of a f32x4 (rows j) -> rows across lanes
__device__ __forceinline__ f32x4 xpose4(f32x4 v, int q) {
    f32x4 tt, wv, t2, xv;
    tt[0] = __shfl_xor(v[0], 1, 64); tt[1] = __shfl_xor(v[1], 1, 64);
    tt[2] = __shfl_xor(v[2], 1, 64); tt[3] = __shfl_xor(v[3], 1, 64);
    if (q & 1) { wv[0] = tt[1]; wv[1] = v[1]; wv[2] = tt[3]; wv[3] = v[3]; }
    else       { wv[0] = v[0];  wv[1] = tt[0]; wv[2] = v[2]; wv[3] = tt[2]; }
    t2[0] = __shfl_xor(wv[0], 2, 64); t2[1] = __shfl_xor(wv[1], 2, 64);
    t2[2] = __shfl_xor(wv[2], 2, 64); t2[3] = __shfl_xor(wv[3], 2, 64);
    if (q & 2) { xv[0] = t2[2]; xv[1] = t2[3]; xv[2] = wv[2]; xv[3] = wv[3]; }
    else       { xv[0] = wv[0]; xv[1] = wv[1]; xv[2] = t2[0]; xv[3] = t2[1]; }
    return xv;
}

// ---------------------------------------------------------------------------
// Kernel 1: row L2-normalize feat_k / feat_g (f32), cast to bf16; zero P.
// ---------------------------------------------------------------------------
__global__ void norm_cast_kernel(const float* __restrict__ fk, const float* __restrict__ fg,
                                 __hip_bfloat16* __restrict__ fkb, __hip_bfloat16* __restrict__ fgb,
                                 float* __restrict__ P, int N, int D) {
    int n = blockIdx.x;
    int t = threadIdx.x;
    float xk = fk[(size_t)n * D + t];
    float xg = fg[(size_t)n * D + t];
    float sk = xk * xk, sg = xg * xg;
#pragma unroll
    for (int off = 32; off > 0; off >>= 1) {
        sk += __shfl_xor(sk, off, 64);
        sg += __shfl_xor(sg, off, 64);
    }
    __shared__ float lsk[4], lsg[4];
    int w = t >> 6, l = t & 63;
    if (l == 0) { lsk[w] = sk; lsg[w] = sg; }
    __syncthreads();
    sk = lsk[0] + lsk[1] + lsk[2] + lsk[3];
    sg = lsg[0] + lsg[1] + lsg[2] + lsg[3];
    float rkv = 1.0f / (sqrtf(sk) + EPS_F);
    float rgv = 1.0f / (sqrtf(sg) + EPS_F);
    fkb[(size_t)n * D + t] = __float2bfloat16(xk * rkv);
    fgb[(size_t)n * D + t] = __float2bfloat16(xg * rgv);
    if (t < NPART) P[(size_t)n * NPART + t] = 0.0f;
}

// ---------------------------------------------------------------------------
// Kernel 2: upper-triangle dual Gram GEMM, 128x64 tiles, 4 waves (2x2).
// Block (by,bx) with bx>=2*by computes its s-tile, writes it AND the
// transposed tile (in-register 4x4 transpose / natural f32x4), and emits
// per-block row/col partial maxes to P (no global atomics).
// ---------------------------------------------------------------------------
__global__ __launch_bounds__(NTHREADS) void dual_gram_kernel(
    const __hip_bfloat16* __restrict__ fkb, const __hip_bfloat16* __restrict__ fgb,
    float* __restrict__ out, float* __restrict__ P, int N, int D) {

    __shared__ __align__(16) char smem[49152 + 768];
    int* lmax = (int*)(smem + 49152);   // [0..127] row-max, [128..191] col-max

    int bx = blockIdx.x, by = blockIdx.y;
    if (bx < 2 * by) return;
    int r0 = by * BM, c0 = bx * BN;

    int t = threadIdx.x;
    int w = t >> 6, l = t & 63;
    int wr = w >> 1, wc = w & 1;   // 2x2 wave grid; wave tile = 64 rows x 32 cols
    int lr = l & 15, lg = l >> 4;

    char* lAk = smem;
    char* lAg = smem + 16384;
    char* lBk = smem + 32768;
    char* lBg = smem + 40960;

    f32x4 acck[4][2], accg[4][2];
    f32x4 zero = {0.f, 0.f, 0.f, 0.f};
#pragma unroll
    for (int m = 0; m < 4; ++m)
#pragma unroll
        for (int n = 0; n < 2; ++n) { acck[m][n] = zero; accg[m][n] = zero; }

    const size_t rowbytes = (size_t)D * 2;

    for (int k0 = 0; k0 < D; k0 += BK) {
        // --- stage A tiles (128 rows, 4 chunks) and B tiles (64 rows, 2 chunks)
#pragma unroll
        for (int c = 0; c < 4; ++c) {
            int o = (t + c * NTHREADS) * 16;
            int row = o >> 7;                          // 128 B per LDS row
            int csw = (o & 127) ^ ((row & 7) << 4);    // inverse-swizzled source col
            size_t goff = (size_t)(r0 + row) * rowbytes + (size_t)k0 * 2 + csw;
            int dst = (w << 10) + (c << 12);           // wave-uniform base + lane*16
            gload_lds16((const char*)fkb + goff, lAk + dst);
            gload_lds16((const char*)fgb + goff, lAg + dst);
        }
#pragma unroll
        for (int c = 0; c < 2; ++c) {
            int o = (t + c * NTHREADS) * 16;
            int row = o >> 7;
            int csw = (o & 127) ^ ((row & 7) << 4);
            size_t goff = (size_t)(c0 + row) * rowbytes + (size_t)k0 * 2 + csw;
            int dst = (w << 10) + (c << 12);
            gload_lds16((const char*)fkb + goff, lBk + dst);
            gload_lds16((const char*)fgb + goff, lBg + dst);
        }
        __syncthreads();

#pragma unroll
        for (int kk = 0; kk < BK; kk += 32) {
            int kb = (kk + lg * 8) * 2;
            short8 ak[4], ag[4], bk2[2], bg2[2];
#pragma unroll
            for (int m = 0; m < 4; ++m) {
                int row = wr * 64 + m * 16 + lr;
                int o = (row << 7) + kb;
                o ^= ((row & 7) << 4);
                ak[m] = *(const short8*)(lAk + o);
                ag[m] = *(const short8*)(lAg + o);
            }
#pragma unroll
            for (int n = 0; n < 2; ++n) {
                int row = wc * 32 + n * 16 + lr;
                int o = (row << 7) + kb;
                o ^= ((row & 7) << 4);
                bk2[n] = *(const short8*)(lBk + o);
                bg2[n] = *(const short8*)(lBg + o);
            }
            __builtin_amdgcn_s_setprio(1);
#pragma unroll
            for (int m = 0; m < 4; ++m)
#pragma unroll
                for (int n = 0; n < 2; ++n) {
                    acck[m][n] = __builtin_amdgcn_mfma_f32_16x16x32_bf16(ak[m], bk2[n], acck[m][n], 0, 0, 0);
                    accg[m][n] = __builtin_amdgcn_mfma_f32_16x16x32_bf16(ag[m], bg2[n], accg[m][n], 0, 0, 0);
                }
            __builtin_amdgcn_s_setprio(0);
        }
        __syncthreads();
    }

    // --- epilogue -----------------------------------------------------------
    if (t < 192) lmax[t] = 0;          // positive floats compare as ints

    int lcol[2];
#pragma unroll
    for (int n = 0; n < 2; ++n) lcol[n] = wc * 32 + n * 16 + lr;   // 0..63

    // ratio + diag, in place
#pragma unroll
    for (int m = 0; m < 4; ++m)
#pragma unroll
        for (int j = 0; j < 4; ++j) {
            int lrow = wr * 64 + m * 16 + lg * 4 + j;
#pragma unroll
            for (int n = 0; n < 2; ++n) {
                float dk = acck[m][n][j];
                float dg = accg[m][n][j];
                float s = (dk + 1.0f + EPS_F) * __builtin_amdgcn_rcpf(dg + 1.0f + EPS_F);
                if (r0 + lrow == c0 + lcol[n]) s = NEG_DIAG_F;
                acck[m][n][j] = s;
            }
        }
    __syncthreads();   // lmax init visible

    // row partial maxes
#pragma unroll
    for (int m = 0; m < 4; ++m)
#pragma unroll
        for (int j = 0; j < 4; ++j) {
            float pm = fmaxf(acck[m][0][j], acck[m][1][j]);
#pragma unroll
            for (int off = 1; off < 16; off <<= 1)
                pm = fmaxf(pm, __shfl_xor(pm, off, 64));
            if (lr == 0) atomicMax(&lmax[wr * 64 + m * 16 + lg * 4 + j], __float_as_int(pm));
        }
    // col partial maxes
#pragma unroll
    for (int n = 0; n < 2; ++n) {
        float cm = acck[0][n][0];
#pragma unroll
        for (int m = 0; m < 4; ++m)
#pragma unroll
            for (int j = 0; j < 4; ++j) cm = fmaxf(cm, acck[m][n][j]);
        cm = fmaxf(cm, __shfl_xor(cm, 16, 64));
        cm = fmaxf(cm, __shfl_xor(cm, 32, 64));
        if (lg == 0) atomicMax(&lmax[128 + lcol[n]], __float_as_int(cm));
    }

    // stores: direct tile via in-register 4x4 transpose, transposed tile natural
    int q = lr & 3;
#pragma unroll
    for (int m = 0; m < 4; ++m)
#pragma unroll
        for (int n = 0; n < 2; ++n) {
            f32x4 v = acck[m][n];
            f32x4 xv = xpose4(v, q);
            int drow = r0 + wr * 64 + m * 16 + lg * 4 + q;
            int dcol = c0 + wc * 32 + n * 16 + (lr >> 2) * 4;
            *(f32x4*)(out + (size_t)drow * N + dcol) = xv;
            int trow = c0 + lcol[n];
            int tcol = r0 + wr * 64 + m * 16 + lg * 4;
            *(f32x4*)(out + (size_t)trow * N + tcol) = v;
        }

    __syncthreads();   // lmax atomics done
    if (t < 128) {
        P[(size_t)(r0 + t) * NPART + bx] = __int_as_float(lmax[t]);
    } else if (t < 192) {
        P[(size_t)(c0 + t - 128) * NPART + 64 + by] = __int_as_float(lmax[t]);
    }
}

// ---------------------------------------------------------------------------
// Kernel 3: one block per row: m = max_j P[row][j]; out = exp(out - m).
// ---------------------------------------------------------------------------
__global__ void finalize_kernel(float* __restrict__ out, const float* __restrict__ P, int N) {
    int row = blockIdx.x;
    int t = threadIdx.x;            // 256
    int j = t & 31;
    float m = P[(size_t)row * NPART + j];
    m = fmaxf(m, P[(size_t)row * NPART + 32 + j]);
    m = fmaxf(m, P[(size_t)row * NPART + 64 + j]);
#pragma unroll
    for (int off = 1; off < 32; off <<= 1)
        m = fmaxf(m, __shfl_xor(m, off, 64));
    float4* o4 = (float4*)(out + (size_t)row * N);
    int n4 = N >> 2;
    for (int i = t; i < n4; i += 256) {
        float4 v = o4[i];
        v.x = __expf(v.x - m);
        v.y = __expf(v.y - m);
        v.z = __expf(v.z - m);
        v.w = __expf(v.w - m);
        o4[i] = v;
    }
}

// ---------------------------------------------------------------------------
extern "C" void kernel_launch(void* const* d_in, const int* in_sizes, int n_in,
                              void* d_out, int out_size, void* d_ws, size_t ws_size,
                              hipStream_t stream) {
    const float* fk = (const float*)d_in[1];
    const float* fg = (const float*)d_in[2];
    float* out = (float*)d_out;

    int N = (int)llround(sqrt((double)out_size));   // 4096
    int D = in_sizes[1] / N;                        // 256

    char* ws = (char*)d_ws;
    float* P = (float*)ws;                                          // N*96*4 = 1.5 MB
    __hip_bfloat16* fkb = (__hip_bfloat16*)(ws + (size_t)N * NPART * 4);
    __hip_bfloat16* fgb = (__hip_bfloat16*)(ws + (size_t)N * NPART * 4 + (size_t)N * D * 2);

    norm_cast_kernel<<<N, D, 0, stream>>>(fk, fg, fkb, fgb, P, N, D);

    dual_gram_kernel<<<dim3(N / BN, N / BM), NTHREADS, 0, stream>>>(fkb, fgb, out, P, N, D);

    finalize_kernel<<<N, 256, 0, stream>>>(out, P, N);
}